// Round 11
// baseline (207.129 us; speedup 1.0000x reference)
//
#include <hip/hip_runtime.h>

#define NA 4096
#define NB 4096
#define DIM 256
#define DK 64
#define PSTR 72            // pbuf row stride (bf16 elements)
#define WSTR 68            // wm LDS row stride (f32 elements)
#define NSPLIT 8           // b-range splits (grid.y)
#define BIT (NB / NSPLIT / 64)   // 8 K-iterations per block

typedef __attribute__((ext_vector_type(8))) short bf16x8;
typedef __attribute__((ext_vector_type(4))) float f32x4;
typedef __attribute__((ext_vector_type(4))) unsigned short us4;
typedef __attribute__((ext_vector_type(4))) int i32x4;

static __device__ __forceinline__ float bf2f(unsigned short u) {
    union { unsigned int u; float f; } x;
    x.u = ((unsigned int)u) << 16;
    return x.f;
}
static __device__ __forceinline__ unsigned short f2bf(float f) {
    union { float f; unsigned int u; } x;
    x.f = f;
    unsigned int r = x.u + 0x7fffu + ((x.u >> 16) & 1u);
    return (unsigned short)(r >> 16);
}

// ---------------------------------------------------------------------------
// Fragment-major layouts (lane-contiguous: element for lane l at base+l*8):
//  XF/WF (proj inputs): flat = ((tile*8 + ki)*64 + l)*8 + e
//  QF/KF (attn QK):     flat = (((head*256 + t16)*2 + ks)*64 + l)*8 + e
//  VF (attn PV):        flat = ((((head*64 + t64)*4 + nt)*2 + ks2)*64 + l)*8 + e
// ---------------------------------------------------------------------------

// ---------------------------------------------------------------------------
// prep: fp32 -> (bf16 hi, lo) split, frag-major out (byte-identical to r10).
// ---------------------------------------------------------------------------
__global__ __launch_bounds__(256) void prep_kernel(
    const float* __restrict__ a_z, const float* __restrict__ bv,
    const float* __restrict__ Wq, const float* __restrict__ Wk,
    const float* __restrict__ Wv,
    unsigned short* __restrict__ ah, unsigned short* __restrict__ al,
    unsigned short* __restrict__ bh, unsigned short* __restrict__ bl,
    unsigned short* __restrict__ wh, unsigned short* __restrict__ wl)
{
    const int idx = blockIdx.x * 256 + threadIdx.x;
    const int y = blockIdx.y;
    const float* __restrict__ src;
    unsigned short* __restrict__ dh;
    unsigned short* __restrict__ dl;
    int row, col;
    if (y == 0) {
        src = a_z; dh = ah; dl = al;
        row = (idx >> 9) * 16 + (idx & 15);
        col = ((idx >> 6) & 7) * 32 + ((idx >> 4) & 3) * 8;
    } else if (y == 1) {
        src = bv; dh = bh; dl = bl;
        row = (idx >> 9) * 16 + (idx & 15);
        col = ((idx >> 6) & 7) * 32 + ((idx >> 4) & 3) * 8;
    } else {
        if (idx >= 3 * 8192) return;
        const int m = idx >> 13;
        const int im = idx & 8191;
        src = (m == 0) ? Wq : ((m == 1) ? Wk : Wv);
        dh = wh; dl = wl;
        row = (im >> 9) * 16 + (im & 15);
        col = ((im >> 6) & 7) * 32 + ((im >> 4) & 3) * 8;
    }
    f32x4 v0 = *(const f32x4*)(src + row * DIM + col);
    f32x4 v1 = *(const f32x4*)(src + row * DIM + col + 4);
    bf16x8 h8, l8;
    #pragma unroll
    for (int r = 0; r < 4; ++r) {
        unsigned short h0 = f2bf(v0[r]);
        h8[r] = (short)h0;  l8[r] = (short)f2bf(v0[r] - bf2f(h0));
        unsigned short h1 = f2bf(v1[r]);
        h8[4 + r] = (short)h1;  l8[4 + r] = (short)f2bf(v1[r] - bf2f(h1));
    }
    *(bf16x8*)(dh + idx * 8) = h8;
    *(bf16x8*)(dl + idx * 8) = l8;
}

// ---------------------------------------------------------------------------
// proj: K-loop + LDS-transpose epilogue (byte-identical to r10 passing).
// ---------------------------------------------------------------------------
__global__ __launch_bounds__(256, 2) void proj_kernel(
    const unsigned short* __restrict__ ah, const unsigned short* __restrict__ al,
    const unsigned short* __restrict__ bh, const unsigned short* __restrict__ bl,
    const unsigned short* __restrict__ whc, const unsigned short* __restrict__ wlc,
    unsigned short* __restrict__ qhi, unsigned short* __restrict__ qlo,
    unsigned short* __restrict__ khi, unsigned short* __restrict__ vtout)
{
    __shared__ unsigned short tbuf[4][4][2][16 * 24];  // [wave][nt][hi/lo][n16*24+c]

    const int mat = blockIdx.z;
    const unsigned short* __restrict__ Xh = (mat == 0) ? ah : bh;
    const unsigned short* __restrict__ Xl = (mat == 0) ? al : bl;
    const unsigned short* __restrict__ Wh = whc + mat * 65536;
    const unsigned short* __restrict__ Wl = wlc + mat * 65536;

    const int tid  = threadIdx.x;
    const int wv   = tid >> 6;
    const int lane = tid & 63;
    const int c    = lane & 15;
    const int quad = lane >> 4;
    const int n0 = blockIdx.x * 64;
    const int by = blockIdx.y;

    const unsigned short* xhp = Xh + (n0 >> 4) * 4096 + lane * 8;
    const unsigned short* xlp = Xl + (n0 >> 4) * 4096 + lane * 8;
    const unsigned short* whp = Wh + (by * 4 + wv) * 4096 + lane * 8;
    const unsigned short* wlp = Wl + (by * 4 + wv) * 4096 + lane * 8;

    f32x4 acc[4];
    #pragma unroll
    for (int nt = 0; nt < 4; ++nt) acc[nt] = (f32x4){0.f, 0.f, 0.f, 0.f};

    bf16x8 wAh, wAl, xAh[4], xAl[4];
    bf16x8 wBh, wBl, xBh[4], xBl[4];

    wAh = *(const bf16x8*)(whp);
    wAl = *(const bf16x8*)(wlp);
    #pragma unroll
    for (int nt = 0; nt < 4; ++nt) {
        xAh[nt] = *(const bf16x8*)(xhp + nt * 4096);
        xAl[nt] = *(const bf16x8*)(xlp + nt * 4096);
    }

    #pragma unroll
    for (int kk = 0; kk < 8; kk += 2) {
        wBh = *(const bf16x8*)(whp + (kk + 1) * 512);
        wBl = *(const bf16x8*)(wlp + (kk + 1) * 512);
        #pragma unroll
        for (int nt = 0; nt < 4; ++nt) {
            xBh[nt] = *(const bf16x8*)(xhp + nt * 4096 + (kk + 1) * 512);
            xBl[nt] = *(const bf16x8*)(xlp + nt * 4096 + (kk + 1) * 512);
        }
        #pragma unroll
        for (int nt = 0; nt < 4; ++nt) {
            acc[nt] = __builtin_amdgcn_mfma_f32_16x16x32_bf16(xAh[nt], wAh, acc[nt], 0, 0, 0);
            acc[nt] = __builtin_amdgcn_mfma_f32_16x16x32_bf16(xAl[nt], wAh, acc[nt], 0, 0, 0);
            acc[nt] = __builtin_amdgcn_mfma_f32_16x16x32_bf16(xAh[nt], wAl, acc[nt], 0, 0, 0);
        }
        if (kk + 2 < 8) {
            wAh = *(const bf16x8*)(whp + (kk + 2) * 512);
            wAl = *(const bf16x8*)(wlp + (kk + 2) * 512);
            #pragma unroll
            for (int nt = 0; nt < 4; ++nt) {
                xAh[nt] = *(const bf16x8*)(xhp + nt * 4096 + (kk + 2) * 512);
                xAl[nt] = *(const bf16x8*)(xlp + nt * 4096 + (kk + 2) * 512);
            }
        }
        #pragma unroll
        for (int nt = 0; nt < 4; ++nt) {
            acc[nt] = __builtin_amdgcn_mfma_f32_16x16x32_bf16(xBh[nt], wBh, acc[nt], 0, 0, 0);
            acc[nt] = __builtin_amdgcn_mfma_f32_16x16x32_bf16(xBl[nt], wBh, acc[nt], 0, 0, 0);
            acc[nt] = __builtin_amdgcn_mfma_f32_16x16x32_bf16(xBh[nt], wBl, acc[nt], 0, 0, 0);
        }
    }

    if (mat != 2) {
        #pragma unroll
        for (int nt = 0; nt < 4; ++nt) {
            #pragma unroll
            for (int r = 0; r < 4; ++r) {
                unsigned short h = f2bf(acc[nt][r]);
                tbuf[wv][nt][0][(quad * 4 + r) * 24 + c] = h;
                if (mat == 0)
                    tbuf[wv][nt][1][(quad * 4 + r) * 24 + c] = f2bf(acc[nt][r] - bf2f(h));
            }
        }
        const int ks   = wv >> 1;
        const int sel  = lane >> 5;          // 0=hi, 1=lo (Q only)
        const int rrow = lane & 15;          // n16
        const int gsub = (lane >> 4) & 1;    // 8-col group within wave's 16
        const int lpp  = ((wv & 1) * 2 + gsub) * 16 + rrow;
        #pragma unroll
        for (int nt = 0; nt < 4; ++nt) {
            const int fbase = (((by * 256 + (n0 >> 4) + nt) * 2 + ks) * 64 + lpp) * 8;
            if (mat == 0) {
                bf16x8 frag = *(const bf16x8*)(&tbuf[wv][nt][sel][rrow * 24 + gsub * 8]);
                unsigned short* dst = sel ? qlo : qhi;
                *(bf16x8*)(dst + fbase) = frag;
            } else if (sel == 0) {
                bf16x8 frag = *(const bf16x8*)(&tbuf[wv][nt][0][rrow * 24 + gsub * 8]);
                *(bf16x8*)(khi + fbase) = frag;
            }
        }
    } else {
        #pragma unroll
        for (int nt = 0; nt < 4; ++nt) {
            const int lv = ((nt & 1) * 2 + (quad >> 1)) * 16 + c;
            const int idx = ((((by * 64 + (n0 >> 6)) * 4 + wv) * 2 + (nt >> 1)) * 64 + lv) * 8
                            + (quad & 1) * 4;
            us4 p;
            #pragma unroll
            for (int r = 0; r < 4; ++r) p[r] = f2bf(acc[nt][r]);
            *(us4*)(vtout + idx) = p;
        }
    }
}

// ---------------------------------------------------------------------------
// attn v8 = r9/r10 structure with pbuf SHARED across the two a-tiles:
//  the two a-tiles' P round-trips are sequential, so one pbuf[4][16*PSTR]
//  suffices (softmax-write -> pf-read -> PV per at). Same-wave same-address
//  LDS ops are program-ordered (identical in kind to r5's across-iteration
//  pbuf reuse, passing since r5). LDS 35.8 -> 26.6 KB; occupancy tracks LDS
//  inversely across rounds (17.9KB:27%, 35.8KB:17%) -> expect ~+40% waves.
//  No register or global-load-order changes (the r7/r8 failure modes).
// ---------------------------------------------------------------------------
__global__ __launch_bounds__(256, 2) void attn_kernel(
    const unsigned short* __restrict__ qhg,
    const unsigned short* __restrict__ qlg,
    const unsigned short* __restrict__ kg,
    const unsigned short* __restrict__ vtg,
    const float* __restrict__ wg,
    const int* __restrict__ mg,
    float* __restrict__ pnum,
    float* __restrict__ pden)
{
    __shared__ float wmbuf[2][32 * WSTR];
    __shared__ unsigned short pbuf[4][16 * PSTR];

    const int tid  = threadIdx.x;
    const int wv   = tid >> 6;      // head
    const int lane = tid & 63;
    const int c    = lane & 15;
    const int quad = lane >> 4;

    const int flat = blockIdx.y * 128 + blockIdx.x;
    const int swz  = (flat & 7) * 128 + (flat >> 3);
    const int a0   = (swz & 127) * 32;
    const int bs   = swz >> 7;
    const int bbase = bs * (NB / NSPLIT);

    const int sa = tid >> 3;
    const int sb = (tid & 7) * 8;

    unsigned kbase = (unsigned)((wv * 256 + (bbase >> 4)) * 1024 + lane * 8);
    unsigned vbase = (unsigned)((wv * 64 + (bbase >> 6)) * 4096 + lane * 8);
    const unsigned qbase = (unsigned)((wv * 256 + (a0 >> 4)) * 1024 + lane * 8);

    bf16x8 qh[2][2], ql[2][2];
    #pragma unroll
    for (int at = 0; at < 2; ++at) {
        qh[at][0] = *(const bf16x8*)(qhg + qbase + at * 1024);
        qh[at][1] = *(const bf16x8*)(qhg + qbase + at * 1024 + 512);
        ql[at][0] = *(const bf16x8*)(qlg + qbase + at * 1024);
        ql[at][1] = *(const bf16x8*)(qlg + qbase + at * 1024 + 512);
    }

    bf16x8 ones;
    #pragma unroll
    for (int r = 0; r < 8; ++r) ones[r] = (short)0x3F80;

    f32x4 num[2][4];
    f32x4 dacc[2];
    #pragma unroll
    for (int at = 0; at < 2; ++at) {
        #pragma unroll
        for (int nt = 0; nt < 4; ++nt) num[at][nt] = (f32x4){0.f, 0.f, 0.f, 0.f};
        dacc[at] = (f32x4){0.f, 0.f, 0.f, 0.f};
    }

    unsigned woff = (unsigned)((a0 + sa) * NB + bbase + sb);

    {
        f32x4 w0 = *(const f32x4*)(wg + woff);
        f32x4 w1 = *(const f32x4*)(wg + woff + 4);
        i32x4 m0 = *(const i32x4*)(mg + woff);
        i32x4 m1 = *(const i32x4*)(mg + woff + 4);
        f32x4 wma, wmb;
        #pragma unroll
        for (int r = 0; r < 4; ++r) {
            wma[r] = m0[r] ? w0[r] : -1.0e9f;
            wmb[r] = m1[r] ? w1[r] : -1.0e9f;
        }
        *(f32x4*)(&wmbuf[0][sa * WSTR + sb])     = wma;
        *(f32x4*)(&wmbuf[0][sa * WSTR + sb + 4]) = wmb;
    }
    woff += 64;

    for (int it = 0; it < BIT; ++it) {
        const int cur = it & 1;
        const bool more = (it + 1 < BIT);
        __syncthreads();

        bf16x8 kf[4][2];
        #pragma unroll
        for (int bt = 0; bt < 4; ++bt)
            #pragma unroll
            for (int ks = 0; ks < 2; ++ks)
                kf[bt][ks] = *(const bf16x8*)(kg + kbase + bt * 1024 + ks * 512);
        __builtin_amdgcn_sched_barrier(0);

        bf16x8 vf[4][2];
        #pragma unroll
        for (int nt = 0; nt < 4; ++nt)
            #pragma unroll
            for (int ks2 = 0; ks2 < 2; ++ks2)
                vf[nt][ks2] = *(const bf16x8*)(vtg + vbase + nt * 1024 + ks2 * 512);
        __builtin_amdgcn_sched_barrier(0);

        f32x4 wn0, wn1; i32x4 mn0, mn1;
        if (more) {
            wn0 = *(const f32x4*)(wg + woff);
            wn1 = *(const f32x4*)(wg + woff + 4);
            mn0 = *(const i32x4*)(mg + woff);
            mn1 = *(const i32x4*)(mg + woff + 4);
        }
        __builtin_amdgcn_sched_barrier(0);

        kbase += 4096; vbase += 4096; woff += 64;

        // QK for both a-tiles
        f32x4 S[2][4];
        __builtin_amdgcn_s_setprio(1);
        #pragma unroll
        for (int at = 0; at < 2; ++at)
            #pragma unroll
            for (int bt = 0; bt < 4; ++bt) {
                f32x4 s = (f32x4){0.f, 0.f, 0.f, 0.f};
                s = __builtin_amdgcn_mfma_f32_16x16x32_bf16(kf[bt][0], qh[at][0], s, 0, 0, 0);
                s = __builtin_amdgcn_mfma_f32_16x16x32_bf16(kf[bt][1], qh[at][1], s, 0, 0, 0);
                s = __builtin_amdgcn_mfma_f32_16x16x32_bf16(kf[bt][0], ql[at][0], s, 0, 0, 0);
                s = __builtin_amdgcn_mfma_f32_16x16x32_bf16(kf[bt][1], ql[at][1], s, 0, 0, 0);
                S[at][bt] = s;
            }
        __builtin_amdgcn_s_setprio(0);

        // per a-tile: softmax-write -> pf-read -> PV (pbuf reused across at;
        // same-wave LDS ops are program-ordered, no barrier needed)
        #pragma unroll
        for (int at = 0; at < 2; ++at) {
            #pragma unroll
            for (int bt = 0; bt < 4; ++bt) {
                f32x4 wf = *(const f32x4*)(&wmbuf[cur][(at * 16 + c) * WSTR + bt * 16 + quad * 4]);
                us4 p;
                #pragma unroll
                for (int r = 0; r < 4; ++r) {
                    float t = fmaf(S[at][bt][r], 0.125f, wf[r]);
                    t = __builtin_amdgcn_fmed3f(t, -10.0f, 10.0f);
                    float e = exp2f(t * 1.4426950408889634f);
                    p[r] = f2bf(e);
                }
                *(us4*)(&pbuf[wv][c * PSTR + bt * 16 + quad * 4]) = p;
            }
            bf16x8 pf[2];
            #pragma unroll
            for (int ks2 = 0; ks2 < 2; ++ks2)
                pf[ks2] = *(const bf16x8*)(&pbuf[wv][c * PSTR + ks2 * 32 + quad * 8]);
            __builtin_amdgcn_s_setprio(1);
            #pragma unroll
            for (int nt = 0; nt < 4; ++nt) {
                num[at][nt] = __builtin_amdgcn_mfma_f32_16x16x32_bf16(pf[0], vf[nt][0], num[at][nt], 0, 0, 0);
                num[at][nt] = __builtin_amdgcn_mfma_f32_16x16x32_bf16(pf[1], vf[nt][1], num[at][nt], 0, 0, 0);
            }
            dacc[at] = __builtin_amdgcn_mfma_f32_16x16x32_bf16(pf[0], ones, dacc[at], 0, 0, 0);
            dacc[at] = __builtin_amdgcn_mfma_f32_16x16x32_bf16(pf[1], ones, dacc[at], 0, 0, 0);
            __builtin_amdgcn_s_setprio(0);
        }

        if (more) {
            f32x4 wma, wmb;
            #pragma unroll
            for (int r = 0; r < 4; ++r) {
                wma[r] = mn0[r] ? wn0[r] : -1.0e9f;
                wmb[r] = mn1[r] ? wn1[r] : -1.0e9f;
            }
            *(f32x4*)(&wmbuf[cur ^ 1][sa * WSTR + sb])     = wma;
            *(f32x4*)(&wmbuf[cur ^ 1][sa * WSTR + sb + 4]) = wmb;
        }
    }

    #pragma unroll
    for (int at = 0; at < 2; ++at) {
        const int hb = (bs * 4 + wv) * NA + a0 + at * 16;
        if (c == 0) {
            #pragma unroll
            for (int r = 0; r < 4; ++r)
                pden[hb + quad * 4 + r] = dacc[at][r];
        }
        #pragma unroll
        for (int nt = 0; nt < 4; ++nt)
            #pragma unroll
            for (int r = 0; r < 4; ++r)
                pnum[(size_t)(hb + quad * 4 + r) * DK + nt * 16 + c] = num[at][nt][r];
    }
}

// ---------------------------------------------------------------------------
// reduce: combine b-split partials, divide, average heads; influence = 1.0
// ---------------------------------------------------------------------------
__global__ __launch_bounds__(256) void reduce_kernel(
    const float* __restrict__ pnum, const float* __restrict__ pden,
    float* __restrict__ outp)
{
    const int idx = blockIdx.x * 256 + threadIdx.x;   // over NA*DK
    const int a = idx >> 6, dd = idx & 63;
    float s = 0.0f;
    #pragma unroll
    for (int h = 0; h < 4; ++h) {
        float n = 0.0f, d = 0.0f;
        #pragma unroll
        for (int b = 0; b < NSPLIT; ++b) {
            n += pnum[(size_t)((b * 4 + h) * NA + a) * DK + dd];
            d += pden[(b * 4 + h) * NA + a];
        }
        s += n / d;
    }
    outp[idx] = 0.25f * s;
    if (dd == 0) outp[NA * DK + a] = 1.0f;   // softmax rows sum to 1
}

extern "C" void kernel_launch(void* const* d_in, const int* in_sizes, int n_in,
                              void* d_out, int out_size, void* d_ws, size_t ws_size,
                              hipStream_t stream) {
    const float* a_z = (const float*)d_in[0];
    const float* bv  = (const float*)d_in[1];
    const int* mask  = (const int*)d_in[2];
    const float* wgt = (const float*)d_in[3];
    const float* Wq  = (const float*)d_in[4];
    const float* Wk  = (const float*)d_in[5];
    const float* Wv  = (const float*)d_in[6];
    float* out = (float*)d_out;

    // persistent attn inputs
    unsigned short* qhi = (unsigned short*)d_ws;       // QF hi [4][256][2][64][8]
    unsigned short* qlo = qhi + NA * DIM;              // QF lo
    unsigned short* khi = qlo + NA * DIM;              // KF
    unsigned short* vt  = khi + NB * DIM;              // VF
    float* pnum = (float*)(vt + (size_t)DIM * NB);     // [NSPLIT][4][NA][DK]
    float* pden = pnum + (size_t)NSPLIT * 4 * NA * DK; // [NSPLIT][4][NA]
    // prep/proj scratch overlapped INSIDE pnum (proj finishes before attn
    // writes pnum; stream-ordered => safe). Span 9.2 MB < pnum 33.5 MB.
    unsigned short* ah  = (unsigned short*)pnum;       // XF a hi
    unsigned short* al  = ah + NA * DIM;
    unsigned short* bh  = al + NA * DIM;
    unsigned short* bl  = bh + NB * DIM;
    unsigned short* whc = bl + NB * DIM;               // WF [3][16][8][64][8]
    unsigned short* wlc = whc + 3 * 65536;

    prep_kernel<<<dim3(512, 3), 256, 0, stream>>>(a_z, bv, Wq, Wk, Wv,
                                                  ah, al, bh, bl, whc, wlc);
    proj_kernel<<<dim3(64, 4, 3), 256, 0, stream>>>(ah, al, bh, bl, whc, wlc,
                                                    qhi, qlo, khi, vt);
    attn_kernel<<<dim3(128, NSPLIT), 256, 0, stream>>>(qhi, qlo, khi, vt,
                                                       wgt, mask, pnum, pden);
    reduce_kernel<<<dim3(NA * DK / 256), 256, 0, stream>>>(pnum, pden, out);
}

// Round 13
// 204.356 us; speedup vs baseline: 1.0136x; 1.0136x over previous
//
#include <hip/hip_runtime.h>

#define NA 4096
#define NB 4096
#define DIM 256
#define DK 64
#define PSTR 72            // pbuf row stride (bf16 elements)
#define WSTR 68            // wm LDS row stride (f32 elements)
#define NSPLIT 8           // b-range splits (grid.y)
#define BIT (NB / NSPLIT / 64)   // 8 K-iterations per block

typedef __attribute__((ext_vector_type(8))) short bf16x8;
typedef __attribute__((ext_vector_type(4))) float f32x4;
typedef __attribute__((ext_vector_type(4))) unsigned short us4;
typedef __attribute__((ext_vector_type(4))) int i32x4;

static __device__ __forceinline__ float bf2f(unsigned short u) {
    union { unsigned int u; float f; } x;
    x.u = ((unsigned int)u) << 16;
    return x.f;
}
static __device__ __forceinline__ unsigned short f2bf(float f) {
    union { float f; unsigned int u; } x;
    x.f = f;
    unsigned int r = x.u + 0x7fffu + ((x.u >> 16) & 1u);
    return (unsigned short)(r >> 16);
}

// ---------------------------------------------------------------------------
// Fragment-major layouts (lane-contiguous: element for lane l at base+l*8):
//  XF/WF (proj inputs): flat = ((tile*8 + ki)*64 + l)*8 + e
//  QF/KF (attn QK):     flat = (((head*256 + t16)*2 + ks)*64 + l)*8 + e
//  VF (attn PV):        flat = ((((head*64 + t64)*4 + nt)*2 + ks2)*64 + l)*8 + e
// ---------------------------------------------------------------------------

// ---------------------------------------------------------------------------
// prep: fp32 -> (bf16 hi, lo) split, frag-major out (byte-identical to r11).
// ---------------------------------------------------------------------------
__global__ __launch_bounds__(256) void prep_kernel(
    const float* __restrict__ a_z, const float* __restrict__ bv,
    const float* __restrict__ Wq, const float* __restrict__ Wk,
    const float* __restrict__ Wv,
    unsigned short* __restrict__ ah, unsigned short* __restrict__ al,
    unsigned short* __restrict__ bh, unsigned short* __restrict__ bl,
    unsigned short* __restrict__ wh, unsigned short* __restrict__ wl)
{
    const int idx = blockIdx.x * 256 + threadIdx.x;
    const int y = blockIdx.y;
    const float* __restrict__ src;
    unsigned short* __restrict__ dh;
    unsigned short* __restrict__ dl;
    int row, col;
    if (y == 0) {
        src = a_z; dh = ah; dl = al;
        row = (idx >> 9) * 16 + (idx & 15);
        col = ((idx >> 6) & 7) * 32 + ((idx >> 4) & 3) * 8;
    } else if (y == 1) {
        src = bv; dh = bh; dl = bl;
        row = (idx >> 9) * 16 + (idx & 15);
        col = ((idx >> 6) & 7) * 32 + ((idx >> 4) & 3) * 8;
    } else {
        if (idx >= 3 * 8192) return;
        const int m = idx >> 13;
        const int im = idx & 8191;
        src = (m == 0) ? Wq : ((m == 1) ? Wk : Wv);
        dh = wh; dl = wl;
        row = (im >> 9) * 16 + (im & 15);
        col = ((im >> 6) & 7) * 32 + ((im >> 4) & 3) * 8;
    }
    f32x4 v0 = *(const f32x4*)(src + row * DIM + col);
    f32x4 v1 = *(const f32x4*)(src + row * DIM + col + 4);
    bf16x8 h8, l8;
    #pragma unroll
    for (int r = 0; r < 4; ++r) {
        unsigned short h0 = f2bf(v0[r]);
        h8[r] = (short)h0;  l8[r] = (short)f2bf(v0[r] - bf2f(h0));
        unsigned short h1 = f2bf(v1[r]);
        h8[4 + r] = (short)h1;  l8[4 + r] = (short)f2bf(v1[r] - bf2f(h1));
    }
    *(bf16x8*)(dh + idx * 8) = h8;
    *(bf16x8*)(dl + idx * 8) = l8;
}

// ---------------------------------------------------------------------------
// proj: K-loop + LDS-transpose epilogue (byte-identical to r11 passing).
// ---------------------------------------------------------------------------
__global__ __launch_bounds__(256, 2) void proj_kernel(
    const unsigned short* __restrict__ ah, const unsigned short* __restrict__ al,
    const unsigned short* __restrict__ bh, const unsigned short* __restrict__ bl,
    const unsigned short* __restrict__ whc, const unsigned short* __restrict__ wlc,
    unsigned short* __restrict__ qhi, unsigned short* __restrict__ qlo,
    unsigned short* __restrict__ khi, unsigned short* __restrict__ vtout)
{
    __shared__ unsigned short tbuf[4][4][2][16 * 24];  // [wave][nt][hi/lo][n16*24+c]

    const int mat = blockIdx.z;
    const unsigned short* __restrict__ Xh = (mat == 0) ? ah : bh;
    const unsigned short* __restrict__ Xl = (mat == 0) ? al : bl;
    const unsigned short* __restrict__ Wh = whc + mat * 65536;
    const unsigned short* __restrict__ Wl = wlc + mat * 65536;

    const int tid  = threadIdx.x;
    const int wv   = tid >> 6;
    const int lane = tid & 63;
    const int c    = lane & 15;
    const int quad = lane >> 4;
    const int n0 = blockIdx.x * 64;
    const int by = blockIdx.y;

    const unsigned short* xhp = Xh + (n0 >> 4) * 4096 + lane * 8;
    const unsigned short* xlp = Xl + (n0 >> 4) * 4096 + lane * 8;
    const unsigned short* whp = Wh + (by * 4 + wv) * 4096 + lane * 8;
    const unsigned short* wlp = Wl + (by * 4 + wv) * 4096 + lane * 8;

    f32x4 acc[4];
    #pragma unroll
    for (int nt = 0; nt < 4; ++nt) acc[nt] = (f32x4){0.f, 0.f, 0.f, 0.f};

    bf16x8 wAh, wAl, xAh[4], xAl[4];
    bf16x8 wBh, wBl, xBh[4], xBl[4];

    wAh = *(const bf16x8*)(whp);
    wAl = *(const bf16x8*)(wlp);
    #pragma unroll
    for (int nt = 0; nt < 4; ++nt) {
        xAh[nt] = *(const bf16x8*)(xhp + nt * 4096);
        xAl[nt] = *(const bf16x8*)(xlp + nt * 4096);
    }

    #pragma unroll
    for (int kk = 0; kk < 8; kk += 2) {
        wBh = *(const bf16x8*)(whp + (kk + 1) * 512);
        wBl = *(const bf16x8*)(wlp + (kk + 1) * 512);
        #pragma unroll
        for (int nt = 0; nt < 4; ++nt) {
            xBh[nt] = *(const bf16x8*)(xhp + nt * 4096 + (kk + 1) * 512);
            xBl[nt] = *(const bf16x8*)(xlp + nt * 4096 + (kk + 1) * 512);
        }
        #pragma unroll
        for (int nt = 0; nt < 4; ++nt) {
            acc[nt] = __builtin_amdgcn_mfma_f32_16x16x32_bf16(xAh[nt], wAh, acc[nt], 0, 0, 0);
            acc[nt] = __builtin_amdgcn_mfma_f32_16x16x32_bf16(xAl[nt], wAh, acc[nt], 0, 0, 0);
            acc[nt] = __builtin_amdgcn_mfma_f32_16x16x32_bf16(xAh[nt], wAl, acc[nt], 0, 0, 0);
        }
        if (kk + 2 < 8) {
            wAh = *(const bf16x8*)(whp + (kk + 2) * 512);
            wAl = *(const bf16x8*)(wlp + (kk + 2) * 512);
            #pragma unroll
            for (int nt = 0; nt < 4; ++nt) {
                xAh[nt] = *(const bf16x8*)(xhp + nt * 4096 + (kk + 2) * 512);
                xAl[nt] = *(const bf16x8*)(xlp + nt * 4096 + (kk + 2) * 512);
            }
        }
        #pragma unroll
        for (int nt = 0; nt < 4; ++nt) {
            acc[nt] = __builtin_amdgcn_mfma_f32_16x16x32_bf16(xBh[nt], wBh, acc[nt], 0, 0, 0);
            acc[nt] = __builtin_amdgcn_mfma_f32_16x16x32_bf16(xBl[nt], wBh, acc[nt], 0, 0, 0);
            acc[nt] = __builtin_amdgcn_mfma_f32_16x16x32_bf16(xBh[nt], wBl, acc[nt], 0, 0, 0);
        }
    }

    if (mat != 2) {
        #pragma unroll
        for (int nt = 0; nt < 4; ++nt) {
            #pragma unroll
            for (int r = 0; r < 4; ++r) {
                unsigned short h = f2bf(acc[nt][r]);
                tbuf[wv][nt][0][(quad * 4 + r) * 24 + c] = h;
                if (mat == 0)
                    tbuf[wv][nt][1][(quad * 4 + r) * 24 + c] = f2bf(acc[nt][r] - bf2f(h));
            }
        }
        const int ks   = wv >> 1;
        const int sel  = lane >> 5;          // 0=hi, 1=lo (Q only)
        const int rrow = lane & 15;          // n16
        const int gsub = (lane >> 4) & 1;    // 8-col group within wave's 16
        const int lpp  = ((wv & 1) * 2 + gsub) * 16 + rrow;
        #pragma unroll
        for (int nt = 0; nt < 4; ++nt) {
            const int fbase = (((by * 256 + (n0 >> 4) + nt) * 2 + ks) * 64 + lpp) * 8;
            if (mat == 0) {
                bf16x8 frag = *(const bf16x8*)(&tbuf[wv][nt][sel][rrow * 24 + gsub * 8]);
                unsigned short* dst = sel ? qlo : qhi;
                *(bf16x8*)(dst + fbase) = frag;
            } else if (sel == 0) {
                bf16x8 frag = *(const bf16x8*)(&tbuf[wv][nt][0][rrow * 24 + gsub * 8]);
                *(bf16x8*)(khi + fbase) = frag;
            }
        }
    } else {
        #pragma unroll
        for (int nt = 0; nt < 4; ++nt) {
            const int lv = ((nt & 1) * 2 + (quad >> 1)) * 16 + c;
            const int idx = ((((by * 64 + (n0 >> 6)) * 4 + wv) * 2 + (nt >> 1)) * 64 + lv) * 8
                            + (quad & 1) * 4;
            us4 p;
            #pragma unroll
            for (int r = 0; r < 4; ++r) p[r] = f2bf(acc[nt][r]);
            *(us4*)(vtout + idx) = p;
        }
    }
}

// ---------------------------------------------------------------------------
// attn v9 = r11 with ONE change: exp2f -> __builtin_amdgcn_exp2f (raw
// v_exp_f32). exp2f lowers to the OCML sequence (range/denorm fixup, ~6-10
// VALU per call); at 64 exps/wave-iter that is ~500 hidden VALU instr/iter —
// the dominant VALU term (VALUBusy 39% vs my 400-instr body estimate).
// Our argument is clamped to |x| <= 14.43 where OCML's core path IS
// v_exp_f32 -> bit-identical result, no denorm/overflow/NaN. Everything
// else byte-identical to r11 (t chain, pack, loads, staging, epilogue).
// ---------------------------------------------------------------------------
__global__ __launch_bounds__(256, 2) void attn_kernel(
    const unsigned short* __restrict__ qhg,
    const unsigned short* __restrict__ qlg,
    const unsigned short* __restrict__ kg,
    const unsigned short* __restrict__ vtg,
    const float* __restrict__ wg,
    const int* __restrict__ mg,
    float* __restrict__ pnum,
    float* __restrict__ pden)
{
    __shared__ float wmbuf[2][32 * WSTR];
    __shared__ unsigned short pbuf[4][16 * PSTR];

    const int tid  = threadIdx.x;
    const int wv   = tid >> 6;      // head
    const int lane = tid & 63;
    const int c    = lane & 15;
    const int quad = lane >> 4;

    const int flat = blockIdx.y * 128 + blockIdx.x;
    const int swz  = (flat & 7) * 128 + (flat >> 3);
    const int a0   = (swz & 127) * 32;
    const int bs   = swz >> 7;
    const int bbase = bs * (NB / NSPLIT);

    const int sa = tid >> 3;
    const int sb = (tid & 7) * 8;

    unsigned kbase = (unsigned)((wv * 256 + (bbase >> 4)) * 1024 + lane * 8);
    unsigned vbase = (unsigned)((wv * 64 + (bbase >> 6)) * 4096 + lane * 8);
    const unsigned qbase = (unsigned)((wv * 256 + (a0 >> 4)) * 1024 + lane * 8);

    bf16x8 qh[2][2], ql[2][2];
    #pragma unroll
    for (int at = 0; at < 2; ++at) {
        qh[at][0] = *(const bf16x8*)(qhg + qbase + at * 1024);
        qh[at][1] = *(const bf16x8*)(qhg + qbase + at * 1024 + 512);
        ql[at][0] = *(const bf16x8*)(qlg + qbase + at * 1024);
        ql[at][1] = *(const bf16x8*)(qlg + qbase + at * 1024 + 512);
    }

    bf16x8 ones;
    #pragma unroll
    for (int r = 0; r < 8; ++r) ones[r] = (short)0x3F80;

    f32x4 num[2][4];
    f32x4 dacc[2];
    #pragma unroll
    for (int at = 0; at < 2; ++at) {
        #pragma unroll
        for (int nt = 0; nt < 4; ++nt) num[at][nt] = (f32x4){0.f, 0.f, 0.f, 0.f};
        dacc[at] = (f32x4){0.f, 0.f, 0.f, 0.f};
    }

    unsigned woff = (unsigned)((a0 + sa) * NB + bbase + sb);

    {
        f32x4 w0 = *(const f32x4*)(wg + woff);
        f32x4 w1 = *(const f32x4*)(wg + woff + 4);
        i32x4 m0 = *(const i32x4*)(mg + woff);
        i32x4 m1 = *(const i32x4*)(mg + woff + 4);
        f32x4 wma, wmb;
        #pragma unroll
        for (int r = 0; r < 4; ++r) {
            wma[r] = m0[r] ? w0[r] : -1.0e9f;
            wmb[r] = m1[r] ? w1[r] : -1.0e9f;
        }
        *(f32x4*)(&wmbuf[0][sa * WSTR + sb])     = wma;
        *(f32x4*)(&wmbuf[0][sa * WSTR + sb + 4]) = wmb;
    }
    woff += 64;

    for (int it = 0; it < BIT; ++it) {
        const int cur = it & 1;
        const bool more = (it + 1 < BIT);
        __syncthreads();

        bf16x8 kf[4][2];
        #pragma unroll
        for (int bt = 0; bt < 4; ++bt)
            #pragma unroll
            for (int ks = 0; ks < 2; ++ks)
                kf[bt][ks] = *(const bf16x8*)(kg + kbase + bt * 1024 + ks * 512);
        __builtin_amdgcn_sched_barrier(0);

        bf16x8 vf[4][2];
        #pragma unroll
        for (int nt = 0; nt < 4; ++nt)
            #pragma unroll
            for (int ks2 = 0; ks2 < 2; ++ks2)
                vf[nt][ks2] = *(const bf16x8*)(vtg + vbase + nt * 1024 + ks2 * 512);
        __builtin_amdgcn_sched_barrier(0);

        f32x4 wn0, wn1; i32x4 mn0, mn1;
        if (more) {
            wn0 = *(const f32x4*)(wg + woff);
            wn1 = *(const f32x4*)(wg + woff + 4);
            mn0 = *(const i32x4*)(mg + woff);
            mn1 = *(const i32x4*)(mg + woff + 4);
        }
        __builtin_amdgcn_sched_barrier(0);

        kbase += 4096; vbase += 4096; woff += 64;

        // QK for both a-tiles
        f32x4 S[2][4];
        __builtin_amdgcn_s_setprio(1);
        #pragma unroll
        for (int at = 0; at < 2; ++at)
            #pragma unroll
            for (int bt = 0; bt < 4; ++bt) {
                f32x4 s = (f32x4){0.f, 0.f, 0.f, 0.f};
                s = __builtin_amdgcn_mfma_f32_16x16x32_bf16(kf[bt][0], qh[at][0], s, 0, 0, 0);
                s = __builtin_amdgcn_mfma_f32_16x16x32_bf16(kf[bt][1], qh[at][1], s, 0, 0, 0);
                s = __builtin_amdgcn_mfma_f32_16x16x32_bf16(kf[bt][0], ql[at][0], s, 0, 0, 0);
                s = __builtin_amdgcn_mfma_f32_16x16x32_bf16(kf[bt][1], ql[at][1], s, 0, 0, 0);
                S[at][bt] = s;
            }
        __builtin_amdgcn_s_setprio(0);

        // per a-tile: softmax-write -> pf-read -> PV (pbuf reused across at)
        #pragma unroll
        for (int at = 0; at < 2; ++at) {
            #pragma unroll
            for (int bt = 0; bt < 4; ++bt) {
                f32x4 wf = *(const f32x4*)(&wmbuf[cur][(at * 16 + c) * WSTR + bt * 16 + quad * 4]);
                us4 p;
                #pragma unroll
                for (int r = 0; r < 4; ++r) {
                    float t = fmaf(S[at][bt][r], 0.125f, wf[r]);
                    t = __builtin_amdgcn_fmed3f(t, -10.0f, 10.0f);
                    float e = __builtin_amdgcn_exp2f(t * 1.4426950408889634f);
                    p[r] = f2bf(e);
                }
                *(us4*)(&pbuf[wv][c * PSTR + bt * 16 + quad * 4]) = p;
            }
            bf16x8 pf[2];
            #pragma unroll
            for (int ks2 = 0; ks2 < 2; ++ks2)
                pf[ks2] = *(const bf16x8*)(&pbuf[wv][c * PSTR + ks2 * 32 + quad * 8]);
            __builtin_amdgcn_s_setprio(1);
            #pragma unroll
            for (int nt = 0; nt < 4; ++nt) {
                num[at][nt] = __builtin_amdgcn_mfma_f32_16x16x32_bf16(pf[0], vf[nt][0], num[at][nt], 0, 0, 0);
                num[at][nt] = __builtin_amdgcn_mfma_f32_16x16x32_bf16(pf[1], vf[nt][1], num[at][nt], 0, 0, 0);
            }
            dacc[at] = __builtin_amdgcn_mfma_f32_16x16x32_bf16(pf[0], ones, dacc[at], 0, 0, 0);
            dacc[at] = __builtin_amdgcn_mfma_f32_16x16x32_bf16(pf[1], ones, dacc[at], 0, 0, 0);
            __builtin_amdgcn_s_setprio(0);
        }

        if (more) {
            f32x4 wma, wmb;
            #pragma unroll
            for (int r = 0; r < 4; ++r) {
                wma[r] = mn0[r] ? wn0[r] : -1.0e9f;
                wmb[r] = mn1[r] ? wn1[r] : -1.0e9f;
            }
            *(f32x4*)(&wmbuf[cur ^ 1][sa * WSTR + sb])     = wma;
            *(f32x4*)(&wmbuf[cur ^ 1][sa * WSTR + sb + 4]) = wmb;
        }
    }

    #pragma unroll
    for (int at = 0; at < 2; ++at) {
        const int hb = (bs * 4 + wv) * NA + a0 + at * 16;
        if (c == 0) {
            #pragma unroll
            for (int r = 0; r < 4; ++r)
                pden[hb + quad * 4 + r] = dacc[at][r];
        }
        #pragma unroll
        for (int nt = 0; nt < 4; ++nt)
            #pragma unroll
            for (int r = 0; r < 4; ++r)
                pnum[(size_t)(hb + quad * 4 + r) * DK + nt * 16 + c] = num[at][nt][r];
    }
}

// ---------------------------------------------------------------------------
// reduce: combine b-split partials, divide, average heads; influence = 1.0
// ---------------------------------------------------------------------------
__global__ __launch_bounds__(256) void reduce_kernel(
    const float* __restrict__ pnum, const float* __restrict__ pden,
    float* __restrict__ outp)
{
    const int idx = blockIdx.x * 256 + threadIdx.x;   // over NA*DK
    const int a = idx >> 6, dd = idx & 63;
    float s = 0.0f;
    #pragma unroll
    for (int h = 0; h < 4; ++h) {
        float n = 0.0f, d = 0.0f;
        #pragma unroll
        for (int b = 0; b < NSPLIT; ++b) {
            n += pnum[(size_t)((b * 4 + h) * NA + a) * DK + dd];
            d += pden[(b * 4 + h) * NA + a];
        }
        s += n / d;
    }
    outp[idx] = 0.25f * s;
    if (dd == 0) outp[NA * DK + a] = 1.0f;   // softmax rows sum to 1
}

extern "C" void kernel_launch(void* const* d_in, const int* in_sizes, int n_in,
                              void* d_out, int out_size, void* d_ws, size_t ws_size,
                              hipStream_t stream) {
    const float* a_z = (const float*)d_in[0];
    const float* bv  = (const float*)d_in[1];
    const int* mask  = (const int*)d_in[2];
    const float* wgt = (const float*)d_in[3];
    const float* Wq  = (const float*)d_in[4];
    const float* Wk  = (const float*)d_in[5];
    const float* Wv  = (const float*)d_in[6];
    float* out = (float*)d_out;

    // persistent attn inputs
    unsigned short* qhi = (unsigned short*)d_ws;       // QF hi [4][256][2][64][8]
    unsigned short* qlo = qhi + NA * DIM;              // QF lo
    unsigned short* khi = qlo + NA * DIM;              // KF
    unsigned short* vt  = khi + NB * DIM;              // VF
    float* pnum = (float*)(vt + (size_t)DIM * NB);     // [NSPLIT][4][NA][DK]
    float* pden = pnum + (size_t)NSPLIT * 4 * NA * DK; // [NSPLIT][4][NA]
    // prep/proj scratch overlapped INSIDE pnum (proj finishes before attn
    // writes pnum; stream-ordered => safe). Span 9.2 MB < pnum 33.5 MB.
    unsigned short* ah  = (unsigned short*)pnum;       // XF a hi
    unsigned short* al  = ah + NA * DIM;
    unsigned short* bh  = al + NA * DIM;
    unsigned short* bl  = bh + NB * DIM;
    unsigned short* whc = bl + NB * DIM;               // WF [3][16][8][64][8]
    unsigned short* wlc = whc + 3 * 65536;

    prep_kernel<<<dim3(512, 3), 256, 0, stream>>>(a_z, bv, Wq, Wk, Wv,
                                                  ah, al, bh, bl, whc, wlc);
    proj_kernel<<<dim3(64, 4, 3), 256, 0, stream>>>(ah, al, bh, bl, whc, wlc,
                                                    qhi, qlo, khi, vt);
    attn_kernel<<<dim3(128, NSPLIT), 256, 0, stream>>>(qhi, qlo, khi, vt,
                                                       wgt, mask, pnum, pden);
    reduce_kernel<<<dim3(NA * DK / 256), 256, 0, stream>>>(pnum, pden, out);
}